// Round 14
// baseline (269.087 us; speedup 1.0000x reference)
//
#include <hip/hip_runtime.h>
#include <math.h>

// B=8, C=128, N=4096, d=16, groups=32
// R14 attn: A-fragment reuse. Mega-tile = 128 j; wave = 32-j quarter covering
//   BOTH i-halves -> each V A-frag b128 read feeds 2 PV MFMAs (halves LDS
//   reads, removes the 2x V-read redundancy that set R10-R13's ~1300
//   cyc/tile LDS wall). Single 40KB V buffer, VS=20 shorts (10-dword row
//   stride -> 2-way aliasing = free per m136), ds_write staging (R13's DMA
//   + VS=16 was 8-way conflicted), 2 barriers per 128 j. 2 blocks/CU.
// abf re-tiled [B, C/8, N, 8]: attn stores b64, proj loads 8x b128 instead
//   of 64x b16.

typedef short v8s __attribute__((ext_vector_type(8)));   // 8 bf16 = 4 VGPRs
typedef float v16f __attribute__((ext_vector_type(16))); // 32x32 acc

__device__ __forceinline__ unsigned short f2bf_rne(float f) {
  unsigned u = __float_as_uint(f);
  u += 0x7fffu + ((u >> 16) & 1u);
  return (unsigned short)(u >> 16);
}

__device__ __forceinline__ v8s mk8(unsigned a, unsigned b, unsigned c, unsigned d) {
  union { unsigned u[4]; v8s s; } x;
  x.u[0] = a; x.u[1] = b; x.u[2] = c; x.u[3] = d;
  return x.s;
}

// pack two fp32 -> dword of 2 bf16 (truncation) in ONE v_perm_b32
__device__ __forceinline__ unsigned pack_trunc(float hi, float lo) {
  return __builtin_amdgcn_perm(__float_as_uint(hi), __float_as_uint(lo), 0x07060302u);
}

// tiled V element index: [b][j>>4][c][j&15]
#define VT(b, n, c) (((((size_t)(b) * 256 + ((n) >> 4)) << 7) + (c)) * 16 + ((n) & 15))
// tiled attn-out index: [b][c>>3][n][c&7]
#define AB(b, c, n) ((((size_t)((b) * 16 + ((c) >> 3)) << 12) + (n)) * 8 + ((c) & 7))

// ws byte offsets
#define WSB_MURS   0u
#define WSB_WCATB  4096u       // 160*128 bf16 = 40960
#define WSB_BCAT   49152u      // 160 f32
#define WSB_PWB    65536u      // 128*128 bf16 = 32768
#define WSB_QBF    131072u     // Q^T [B,16,N] bf16 = 1 MB
#define WSB_KBF    1310720u    // K [B,N,16] bf16 = 1 MB
#define WSB_VBF    2621440u    // 8 MB (tiled)
#define WSB_ABF    11534336u   // 8 MB (tiled)

// ---------------------------------------------------------------------------
// gn_stats + prep fused. Grid 256 x 512 thr.
// ---------------------------------------------------------------------------
__global__ __launch_bounds__(512)
void gnprep_kernel(const float* __restrict__ x, float* __restrict__ mu_rs,
                   const float* __restrict__ qw, const float* __restrict__ qb,
                   const float* __restrict__ kw, const float* __restrict__ kb,
                   const float* __restrict__ vw, const float* __restrict__ vb,
                   const float* __restrict__ pw,
                   unsigned short* __restrict__ wcatb, float* __restrict__ bcat,
                   unsigned short* __restrict__ pwb) {
  const int id = blockIdx.x;
  {
    const float qs = 0.36067376022224085f;  // 0.25 * log2(e)
    int idx = id * 512 + threadIdx.x;
    if (idx < 160 * 128) {
      int o = idx >> 7, c = idx & 127;
      float val;
      if (o < 16)       val = qw[o * 128 + c] * qs;
      else if (o < 32)  val = kw[(o - 16) * 128 + c];
      else              val = vw[(o - 32) * 128 + c];
      wcatb[idx] = f2bf_rne(val);
    } else if (idx < 160 * 128 + 160) {
      int o = idx - 160 * 128;
      bcat[o] = (o < 16) ? qb[o] * qs : (o < 32) ? kb[o - 16] : vb[o - 32];
    } else if (idx < 160 * 128 + 160 + 128 * 128) {
      int j = idx - (160 * 128 + 160);
      pwb[j] = f2bf_rne(pw[j]);
    }
  }
  const int bg = (id & 7) * 32 + (id >> 3);   // XCD swizzle: batch = id & 7
  const float4* xp = (const float4*)(x + (size_t)bg * 16384);
  float s = 0.f, ss = 0.f;
#pragma unroll
  for (int u = 0; u < 8; ++u) {
    int i = threadIdx.x + u * 512;
    float4 v = xp[i];
    s  += v.x + v.y + v.z + v.w;
    ss += v.x * v.x + v.y * v.y + v.z * v.z + v.w * v.w;
  }
  for (int off = 32; off > 0; off >>= 1) {
    s  += __shfl_down(s, off, 64);
    ss += __shfl_down(ss, off, 64);
  }
  __shared__ float red[16];
  int lane = threadIdx.x & 63, wid = threadIdx.x >> 6;
  if (lane == 0) { red[wid * 2] = s; red[wid * 2 + 1] = ss; }
  __syncthreads();
  if (threadIdx.x == 0) {
    float S = 0.f, SS = 0.f;
    for (int w = 0; w < 8; ++w) { S += red[w * 2]; SS += red[w * 2 + 1]; }
    float mu  = S * (1.0f / 16384.0f);
    float var = SS * (1.0f / 16384.0f) - mu * mu;
    float rs  = rsqrtf(var + 1e-5f);
    mu_rs[bg * 2]     = mu;
    mu_rs[bg * 2 + 1] = rs;
  }
}

// ---------------------------------------------------------------------------
// QKV as MFMA GEMM, GN fused. Block 512 thr (8 waves), n-tile 64.
// Q stored transposed [B,16,N]. XCD-pinned grid.
// ---------------------------------------------------------------------------
__global__ __launch_bounds__(512)
void qkv_kernel(const float* __restrict__ x, const float* __restrict__ gnw,
                const float* __restrict__ gnb, const float* __restrict__ mu_rs,
                const unsigned short* __restrict__ wcatb, const float* __restrict__ bcat,
                unsigned short* __restrict__ qTb, unsigned short* __restrict__ kbf,
                unsigned short* __restrict__ vbf) {
  __shared__ float scs[128], shs[128], bsh[160];
  const int id = blockIdx.x;
  const int b = id & 7, nb = (id >> 3) << 6;   // XCD-pinned batch
  const int t = threadIdx.x;
  const int w = t >> 6, lane = t & 63, h = lane >> 5, l = lane & 31;
  const int nsub = w & 1, og = w >> 1;
  if (t < 128) {
    float mu = mu_rs[(b * 32 + (t >> 2)) * 2];
    float rs = mu_rs[(b * 32 + (t >> 2)) * 2 + 1];
    float gw = gnw[t], gb = gnb[t];
    scs[t] = rs * gw; shs[t] = gb - mu * rs * gw;
  }
  if (t < 160) bsh[t] = bcat[t];
  __syncthreads();

  const int n = nb + nsub * 32 + l;
  const float* xb = x + ((size_t)b * 128 << 12);
  const int otbase = (og == 0) ? 0 : og + 1;

  float xv[64];
#pragma unroll
  for (int ks = 0; ks < 8; ++ks)
#pragma unroll
    for (int p = 0; p < 8; ++p)
      xv[ks * 8 + p] = xb[((size_t)(ks * 16 + 8 * h + p) << 12) + n];

  v16f acc[2];
#pragma unroll
  for (int a2 = 0; a2 < 2; ++a2)
#pragma unroll
    for (int r = 0; r < 16; ++r) acc[a2][r] = 0.f;

#pragma unroll
  for (int ks = 0; ks < 8; ++ks) {
    const int c0 = ks * 16 + 8 * h;
    unsigned fd[4];
#pragma unroll
    for (int p = 0; p < 4; ++p) {
      int ca = c0 + 2 * p;
      float h0 = xv[ks * 8 + 2 * p]     * scs[ca]     + shs[ca];
      float h1 = xv[ks * 8 + 2 * p + 1] * scs[ca + 1] + shs[ca + 1];
      fd[p] = (unsigned)f2bf_rne(h0) | ((unsigned)f2bf_rne(h1) << 16);
    }
    v8s bf = mk8(fd[0], fd[1], fd[2], fd[3]);
    {
      v8s af = *(const v8s*)(wcatb + (otbase * 32 + l) * 128 + ks * 16 + 8 * h);
      acc[0] = __builtin_amdgcn_mfma_f32_32x32x16_bf16(af, bf, acc[0], 0, 0, 0);
    }
    if (og == 0) {
      v8s af = *(const v8s*)(wcatb + (32 + l) * 128 + ks * 16 + 8 * h);
      acc[1] = __builtin_amdgcn_mfma_f32_32x32x16_bf16(af, bf, acc[1], 0, 0, 0);
    }
  }

  if (og == 0) {
    const size_t nqk = ((size_t)b * 4096 + n) << 4;
#pragma unroll
    for (int r = 0; r < 16; ++r) {
      int o = 4 * h + (r & 3) + 8 * (r >> 2);
      unsigned short bv = f2bf_rne(acc[0][r] + bsh[o]);
      if (o < 16) qTb[((size_t)(b * 16 + o) << 12) + n] = bv;
      else        kbf[nqk + o - 16] = bv;
    }
#pragma unroll
    for (int r = 0; r < 16; ++r) {
      int o = 32 + 4 * h + (r & 3) + 8 * (r >> 2);
      vbf[VT(b, n, o - 32)] = f2bf_rne(acc[1][r] + bsh[o]);
    }
  } else {
#pragma unroll
    for (int r = 0; r < 16; ++r) {
      int o = otbase * 32 + 4 * h + (r & 3) + 8 * (r >> 2);
      vbf[VT(b, n, o - 32)] = f2bf_rne(acc[0][r] + bsh[o]);
    }
  }
}

// ---------------------------------------------------------------------------
// R14 flash attention. Block 256 thr (4 waves) = (batch, 64-i tile), grid
// 512, XCD-pinned. Mega-tile 128 j; wave = j-quarter, both i-halves.
// ---------------------------------------------------------------------------
#define VSD 20   // shorts per V row (16 data + 4 pad); 10-dword stride

__global__ __launch_bounds__(256)
void attn_kernel(const unsigned short* __restrict__ qTb,
                 const unsigned short* __restrict__ kbf,
                 const unsigned short* __restrict__ vbf,
                 unsigned short* __restrict__ abf) {
  __shared__ alignas(16) unsigned short vlds[1024 * VSD];  // 40960 B
  __shared__ float l_lds[64];
  float* const ov = (float*)vlds;   // epilogue overlay (9216 f32 = 36864 B)

  const int id = blockIdx.x;
  const int b = id & 7, i0 = (id >> 3) << 6;   // XCD-pinned batch, 64-i tile
  const int t = threadIdx.x;
  const int w = t >> 6, lane = t & 63, h = lane >> 5, l = lane & 31;

  const unsigned short* kg = kbf + ((size_t)b << 16);
  const unsigned short* vg = vbf + ((size_t)b << 19);

  // Q B-frags for both i-halves from Q^T [B,16,N]
  unsigned qd0[4], qd1[4];
#pragma unroll
  for (int e = 0; e < 4; ++e) {
    size_t rowa = (size_t)(b * 16 + 8 * h + 2 * e) << 12;
    size_t rowb = (size_t)(b * 16 + 8 * h + 2 * e + 1) << 12;
    unsigned lo0 = qTb[rowa + i0 + l],      hi0 = qTb[rowb + i0 + l];
    unsigned lo1 = qTb[rowa + i0 + 32 + l], hi1 = qTb[rowb + i0 + 32 + l];
    qd0[e] = lo0 | (hi0 << 16);
    qd1[e] = lo1 | (hi1 << 16);
  }
  const v8s qf0 = mk8(qd0[0], qd0[1], qd0[2], qd0[3]);
  const v8s qf1 = mk8(qd1[0], qd1[1], qd1[2], qd1[3]);

  v16f zc;
#pragma unroll
  for (int r = 0; r < 16; ++r) zc[r] = 0.f;
  v16f acc[4][2];
#pragma unroll
  for (int ct = 0; ct < 4; ++ct)
#pragma unroll
    for (int ih = 0; ih < 2; ++ih)
#pragma unroll
      for (int r = 0; r < 16; ++r) acc[ct][ih][r] = 0.f;
  float ls0 = 0.f, ls1 = 0.f;

  // staging: thread t covers (c = t>>1, half = t&1) across 8 chunks
  const int sc = t >> 1, shalf = (t & 1) * 8;

  if (t < 64) l_lds[t] = 0.f;

  for (int tile = 0; tile < 32; ++tile) {           // 32 mega-tiles of 128 j
    // global loads into regs: 8 V chunks + this wave's K A-frag
    v8s s[8];
#pragma unroll
    for (int u = 0; u < 8; ++u)
      s[u] = *(const v8s*)(vg + (size_t)tile * 16384 + u * 2048 + sc * 16 + shalf);
    v8s kf = *(const v8s*)(kg + (((size_t)(tile * 128 + w * 32 + l)) << 4) + 8 * h);

    __syncthreads();   // prior PV done reading vlds

#pragma unroll
    for (int u = 0; u < 8; ++u)
      *(v8s*)(&vlds[(u * 128 + sc) * VSD + shalf]) = s[u];

    // QK for both i-halves while writes drain
    v16f st0 = __builtin_amdgcn_mfma_f32_32x32x16_bf16(kf, qf0, zc, 0, 0, 0);
    v16f st1 = __builtin_amdgcn_mfma_f32_32x32x16_bf16(kf, qf1, zc, 0, 0, 0);
    v8s pf[2][2];
    {
      float pe[16];
#pragma unroll
      for (int r = 0; r < 16; ++r) { pe[r] = __builtin_amdgcn_exp2f(st0[r]); ls0 += pe[r]; }
      unsigned G[8];
#pragma unroll
      for (int g = 0; g < 4; ++g) {
        G[2 * g]     = pack_trunc(pe[4 * g + 1], pe[4 * g]);
        G[2 * g + 1] = pack_trunc(pe[4 * g + 3], pe[4 * g + 2]);
      }
      unsigned S0 = h ? G[0] : G[2], S1 = h ? G[1] : G[3];
      unsigned S2 = h ? G[4] : G[6], S3 = h ? G[5] : G[7];
      unsigned R0 = (unsigned)__shfl_xor((int)S0, 32, 64);
      unsigned R1 = (unsigned)__shfl_xor((int)S1, 32, 64);
      unsigned R2 = (unsigned)__shfl_xor((int)S2, 32, 64);
      unsigned R3 = (unsigned)__shfl_xor((int)S3, 32, 64);
      pf[0][0] = h ? mk8(R0, R1, G[2], G[3]) : mk8(G[0], G[1], R0, R1);
      pf[0][1] = h ? mk8(R2, R3, G[6], G[7]) : mk8(G[4], G[5], R2, R3);
    }
    {
      float pe[16];
#pragma unroll
      for (int r = 0; r < 16; ++r) { pe[r] = __builtin_amdgcn_exp2f(st1[r]); ls1 += pe[r]; }
      unsigned G[8];
#pragma unroll
      for (int g = 0; g < 4; ++g) {
        G[2 * g]     = pack_trunc(pe[4 * g + 1], pe[4 * g]);
        G[2 * g + 1] = pack_trunc(pe[4 * g + 3], pe[4 * g + 2]);
      }
      unsigned S0 = h ? G[0] : G[2], S1 = h ? G[1] : G[3];
      unsigned S2 = h ? G[4] : G[6], S3 = h ? G[5] : G[7];
      unsigned R0 = (unsigned)__shfl_xor((int)S0, 32, 64);
      unsigned R1 = (unsigned)__shfl_xor((int)S1, 32, 64);
      unsigned R2 = (unsigned)__shfl_xor((int)S2, 32, 64);
      unsigned R3 = (unsigned)__shfl_xor((int)S3, 32, 64);
      pf[1][0] = h ? mk8(R0, R1, G[2], G[3]) : mk8(G[0], G[1], R0, R1);
      pf[1][1] = h ? mk8(R2, R3, G[6], G[7]) : mk8(G[4], G[5], R2, R3);
    }

    __syncthreads();   // V staged

    // PV: wave's j-quarter = chunks w*2, w*2+1. Each vf read feeds 2 MFMAs.
#pragma unroll
    for (int ks = 0; ks < 2; ++ks)
#pragma unroll
      for (int ct = 0; ct < 4; ++ct) {
        v8s vf = *(const v8s*)(&vlds[((w * 2 + ks) * 128 + ct * 32 + l) * VSD + 8 * h]);
        acc[ct][0] = __builtin_amdgcn_mfma_f32_32x32x16_bf16(vf, pf[0][ks], acc[ct][0], 0, 0, 0);
        acc[ct][1] = __builtin_amdgcn_mfma_f32_32x32x16_bf16(vf, pf[1][ks], acc[ct][1], 0, 0, 0);
      }
  }

  // ---- epilogue ----
  atomicAdd(&l_lds[l], ls0);
  atomicAdd(&l_lds[32 + l], ls1);
  __syncthreads();   // last PV done; vlds dead; l complete

  for (int idx = t; idx < 9216; idx += 256) ov[idx] = 0.f;
  __syncthreads();
  // accumulate 4 waves' partials: group g = ct*2+ih, row i=l, col 4h+(r&3)+8(r>>2)
#pragma unroll
  for (int ct = 0; ct < 4; ++ct)
#pragma unroll
    for (int ih = 0; ih < 2; ++ih)
#pragma unroll
      for (int r = 0; r < 16; ++r)
        atomicAdd(&ov[((ct * 2 + ih) * 32 + l) * 36 + 4 * h + (r & 3) + 8 * (r >> 2)],
                  acc[ct][ih][r]);
  __syncthreads();

  // write out: thread = (group g = t>>5, i = t&31); b64 stores to tiled abf
  {
    const int g = t >> 5, i = t & 31;
    const int ct = g >> 1, ih = g & 1;
    const int n = i0 + ih * 32 + i;
    const float li = 1.f / l_lds[ih * 32 + i];
#pragma unroll
    for (int m = 0; m < 8; ++m) {
      float4 v4 = *(float4*)&ov[(g * 32 + i) * 36 + 4 * m];
      int c = ct * 32 + 4 * m;
      unsigned d0 = (unsigned)f2bf_rne(v4.x * li) | ((unsigned)f2bf_rne(v4.y * li) << 16);
      unsigned d1 = (unsigned)f2bf_rne(v4.z * li) | ((unsigned)f2bf_rne(v4.w * li) << 16);
      uint2 st2; st2.x = d0; st2.y = d1;
      *(uint2*)(abf + AB(b, c, n)) = st2;
    }
  }
}

// ---------------------------------------------------------------------------
// proj as MFMA GEMM + bias + residual. abf read via 8 coalesced b128 loads
// (tiled layout). Block 512 thr, n-tile 64. XCD-pinned grid.
// ---------------------------------------------------------------------------
__global__ __launch_bounds__(512)
void proj_kernel(const unsigned short* __restrict__ abf, const unsigned short* __restrict__ pwb,
                 const float* __restrict__ pb, const float* __restrict__ x,
                 float* __restrict__ out) {
  __shared__ float pbs[128];
  const int id = blockIdx.x;
  const int b = id & 7, nb = (id >> 3) << 6;   // XCD-pinned batch
  const int t = threadIdx.x;
  const int w = t >> 6, lane = t & 63, h = lane >> 5, l = lane & 31;
  const int nsub = w & 1, ot = w >> 1;
  if (t < 128) pbs[t] = pb[t];
  __syncthreads();

  const int n = nb + nsub * 32 + l;

  // 8 B-frags, one b128 each: c-group = ks*2 + h
  v8s bfr[8];
#pragma unroll
  for (int ks = 0; ks < 8; ++ks)
    bfr[ks] = *(const v8s*)(abf + ((((size_t)(b * 16 + ks * 2 + h)) << 12) + n) * 8);

  v16f acc;
#pragma unroll
  for (int r = 0; r < 16; ++r) acc[r] = 0.f;

#pragma unroll
  for (int ks = 0; ks < 8; ++ks) {
    v8s af = *(const v8s*)(pwb + (ot * 32 + l) * 128 + ks * 16 + 8 * h);
    acc = __builtin_amdgcn_mfma_f32_32x32x16_bf16(af, bfr[ks], acc, 0, 0, 0);
  }

#pragma unroll
  for (int r = 0; r < 16; ++r) {
    int e = ot * 32 + 4 * h + (r & 3) + 8 * (r >> 2);
    size_t idx = ((size_t)(b * 128 + e) << 12) + n;
    out[idx] = acc[r] + pbs[e] + x[idx];
  }
}

// ---------------------------------------------------------------------------
extern "C" void kernel_launch(void* const* d_in, const int* in_sizes, int n_in,
                              void* d_out, int out_size, void* d_ws, size_t ws_size,
                              hipStream_t stream) {
  const float* x   = (const float*)d_in[0];
  const float* gnw = (const float*)d_in[1];
  const float* gnb = (const float*)d_in[2];
  const float* qw  = (const float*)d_in[3];
  const float* qb  = (const float*)d_in[4];
  const float* kw  = (const float*)d_in[5];
  const float* kb  = (const float*)d_in[6];
  const float* vw  = (const float*)d_in[7];
  const float* vb  = (const float*)d_in[8];
  const float* pw  = (const float*)d_in[9];
  const float* pb  = (const float*)d_in[10];
  float* out = (float*)d_out;
  char* ws = (char*)d_ws;

  float* mu_rs = (float*)(ws + WSB_MURS);
  unsigned short* wcatb = (unsigned short*)(ws + WSB_WCATB);
  float* bcat = (float*)(ws + WSB_BCAT);
  unsigned short* pwb = (unsigned short*)(ws + WSB_PWB);
  unsigned short* qTb = (unsigned short*)(ws + WSB_QBF);
  unsigned short* kbf = (unsigned short*)(ws + WSB_KBF);
  unsigned short* vbf = (unsigned short*)(ws + WSB_VBF);
  unsigned short* abf = (unsigned short*)(ws + WSB_ABF);

  hipLaunchKernelGGL(gnprep_kernel, dim3(256), dim3(512), 0, stream,
                     x, mu_rs, qw, qb, kw, kb, vw, vb, pw, wcatb, bcat, pwb);
  hipLaunchKernelGGL(qkv_kernel, dim3(512), dim3(512), 0, stream,
                     x, gnw, gnb, mu_rs, wcatb, bcat, qTb, kbf, vbf);
  hipLaunchKernelGGL(attn_kernel, dim3(512), dim3(256), 0, stream,
                     qTb, kbf, vbf, abf);
  hipLaunchKernelGGL(proj_kernel, dim3(512), dim3(512), 0, stream,
                     abf, pwb, pb, x, out);
}

// Round 15
// 163.536 us; speedup vs baseline: 1.6454x; 1.6454x over previous
//
#include <hip/hip_runtime.h>
#include <math.h>

// B=8, C=128, N=4096, d=16, groups=32
// R15 = R12's proven attn loop (66.8 us) + proj FUSED into attn epilogue.
//   - attn j-loop verbatim from R12 (dbuf V staging VS=24, reg-P, K direct,
//     Q^T reads, 1 barrier/tile). DO NOT TOUCH (R13 DMA and R14 restructure
//     both regressed; R12 is the local optimum).
//   - epilogue: jsub-combine as R12, then normalized O written bf16 to LDS
//     O^T[n][c] stride 136 shorts (68 dwords == 4 mod 8 -> conflict-free
//     b128 phases; rows 16B aligned), then all 4 waves do the 128x128x64
//     proj GEMM (pwb A-frags from L2) and store out = acc + pb + x.
//   Deletes: proj launch, abf 8MB write + 8MB read. 3 launches total.

typedef short v8s __attribute__((ext_vector_type(8)));   // 8 bf16 = 4 VGPRs
typedef float v16f __attribute__((ext_vector_type(16))); // 32x32 acc

__device__ __forceinline__ unsigned short f2bf_rne(float f) {
  unsigned u = __float_as_uint(f);
  u += 0x7fffu + ((u >> 16) & 1u);
  return (unsigned short)(u >> 16);
}

__device__ __forceinline__ v8s mk8(unsigned a, unsigned b, unsigned c, unsigned d) {
  union { unsigned u[4]; v8s s; } x;
  x.u[0] = a; x.u[1] = b; x.u[2] = c; x.u[3] = d;
  return x.s;
}

// pack two fp32 -> dword of 2 bf16 (truncation) in ONE v_perm_b32
__device__ __forceinline__ unsigned pack_trunc(float hi, float lo) {
  return __builtin_amdgcn_perm(__float_as_uint(hi), __float_as_uint(lo), 0x07060302u);
}

// tiled V element index: [b][j>>4][c][j&15]
#define VT(b, n, c) (((((size_t)(b) * 256 + ((n) >> 4)) << 7) + (c)) * 16 + ((n) & 15))

// ws byte offsets
#define WSB_MURS   0u
#define WSB_WCATB  4096u       // 160*128 bf16 = 40960
#define WSB_BCAT   49152u      // 160 f32
#define WSB_PWB    65536u      // 128*128 bf16 = 32768
#define WSB_QBF    131072u     // Q^T [B,16,N] bf16 = 1 MB
#define WSB_KBF    1310720u    // K [B,N,16] bf16 = 1 MB
#define WSB_VBF    2621440u    // 8 MB (tiled)

// ---------------------------------------------------------------------------
// gn_stats + prep fused. Grid 256 x 512 thr.
// ---------------------------------------------------------------------------
__global__ __launch_bounds__(512)
void gnprep_kernel(const float* __restrict__ x, float* __restrict__ mu_rs,
                   const float* __restrict__ qw, const float* __restrict__ qb,
                   const float* __restrict__ kw, const float* __restrict__ kb,
                   const float* __restrict__ vw, const float* __restrict__ vb,
                   const float* __restrict__ pw,
                   unsigned short* __restrict__ wcatb, float* __restrict__ bcat,
                   unsigned short* __restrict__ pwb) {
  const int id = blockIdx.x;
  {
    const float qs = 0.36067376022224085f;  // 0.25 * log2(e)
    int idx = id * 512 + threadIdx.x;
    if (idx < 160 * 128) {
      int o = idx >> 7, c = idx & 127;
      float val;
      if (o < 16)       val = qw[o * 128 + c] * qs;
      else if (o < 32)  val = kw[(o - 16) * 128 + c];
      else              val = vw[(o - 32) * 128 + c];
      wcatb[idx] = f2bf_rne(val);
    } else if (idx < 160 * 128 + 160) {
      int o = idx - 160 * 128;
      bcat[o] = (o < 16) ? qb[o] * qs : (o < 32) ? kb[o - 16] : vb[o - 32];
    } else if (idx < 160 * 128 + 160 + 128 * 128) {
      int j = idx - (160 * 128 + 160);
      pwb[j] = f2bf_rne(pw[j]);
    }
  }
  const int bg = (id & 7) * 32 + (id >> 3);   // XCD swizzle: batch = id & 7
  const float4* xp = (const float4*)(x + (size_t)bg * 16384);
  float s = 0.f, ss = 0.f;
#pragma unroll
  for (int u = 0; u < 8; ++u) {
    int i = threadIdx.x + u * 512;
    float4 v = xp[i];
    s  += v.x + v.y + v.z + v.w;
    ss += v.x * v.x + v.y * v.y + v.z * v.z + v.w * v.w;
  }
  for (int off = 32; off > 0; off >>= 1) {
    s  += __shfl_down(s, off, 64);
    ss += __shfl_down(ss, off, 64);
  }
  __shared__ float red[16];
  int lane = threadIdx.x & 63, wid = threadIdx.x >> 6;
  if (lane == 0) { red[wid * 2] = s; red[wid * 2 + 1] = ss; }
  __syncthreads();
  if (threadIdx.x == 0) {
    float S = 0.f, SS = 0.f;
    for (int w = 0; w < 8; ++w) { S += red[w * 2]; SS += red[w * 2 + 1]; }
    float mu  = S * (1.0f / 16384.0f);
    float var = SS * (1.0f / 16384.0f) - mu * mu;
    float rs  = rsqrtf(var + 1e-5f);
    mu_rs[bg * 2]     = mu;
    mu_rs[bg * 2 + 1] = rs;
  }
}

// ---------------------------------------------------------------------------
// QKV as MFMA GEMM, GN fused. Block 512 thr (8 waves), n-tile 64.
// Q stored transposed [B,16,N]. XCD-pinned grid. (R12 verbatim.)
// ---------------------------------------------------------------------------
__global__ __launch_bounds__(512)
void qkv_kernel(const float* __restrict__ x, const float* __restrict__ gnw,
                const float* __restrict__ gnb, const float* __restrict__ mu_rs,
                const unsigned short* __restrict__ wcatb, const float* __restrict__ bcat,
                unsigned short* __restrict__ qTb, unsigned short* __restrict__ kbf,
                unsigned short* __restrict__ vbf) {
  __shared__ float scs[128], shs[128], bsh[160];
  const int id = blockIdx.x;
  const int b = id & 7, nb = (id >> 3) << 6;   // XCD-pinned batch
  const int t = threadIdx.x;
  const int w = t >> 6, lane = t & 63, h = lane >> 5, l = lane & 31;
  const int nsub = w & 1, og = w >> 1;
  if (t < 128) {
    float mu = mu_rs[(b * 32 + (t >> 2)) * 2];
    float rs = mu_rs[(b * 32 + (t >> 2)) * 2 + 1];
    float gw = gnw[t], gb = gnb[t];
    scs[t] = rs * gw; shs[t] = gb - mu * rs * gw;
  }
  if (t < 160) bsh[t] = bcat[t];
  __syncthreads();

  const int n = nb + nsub * 32 + l;
  const float* xb = x + ((size_t)b * 128 << 12);
  const int otbase = (og == 0) ? 0 : og + 1;

  float xv[64];
#pragma unroll
  for (int ks = 0; ks < 8; ++ks)
#pragma unroll
    for (int p = 0; p < 8; ++p)
      xv[ks * 8 + p] = xb[((size_t)(ks * 16 + 8 * h + p) << 12) + n];

  v16f acc[2];
#pragma unroll
  for (int a2 = 0; a2 < 2; ++a2)
#pragma unroll
    for (int r = 0; r < 16; ++r) acc[a2][r] = 0.f;

#pragma unroll
  for (int ks = 0; ks < 8; ++ks) {
    const int c0 = ks * 16 + 8 * h;
    unsigned fd[4];
#pragma unroll
    for (int p = 0; p < 4; ++p) {
      int ca = c0 + 2 * p;
      float h0 = xv[ks * 8 + 2 * p]     * scs[ca]     + shs[ca];
      float h1 = xv[ks * 8 + 2 * p + 1] * scs[ca + 1] + shs[ca + 1];
      fd[p] = (unsigned)f2bf_rne(h0) | ((unsigned)f2bf_rne(h1) << 16);
    }
    v8s bf = mk8(fd[0], fd[1], fd[2], fd[3]);
    {
      v8s af = *(const v8s*)(wcatb + (otbase * 32 + l) * 128 + ks * 16 + 8 * h);
      acc[0] = __builtin_amdgcn_mfma_f32_32x32x16_bf16(af, bf, acc[0], 0, 0, 0);
    }
    if (og == 0) {
      v8s af = *(const v8s*)(wcatb + (32 + l) * 128 + ks * 16 + 8 * h);
      acc[1] = __builtin_amdgcn_mfma_f32_32x32x16_bf16(af, bf, acc[1], 0, 0, 0);
    }
  }

  if (og == 0) {
    const size_t nqk = ((size_t)b * 4096 + n) << 4;
#pragma unroll
    for (int r = 0; r < 16; ++r) {
      int o = 4 * h + (r & 3) + 8 * (r >> 2);
      unsigned short bv = f2bf_rne(acc[0][r] + bsh[o]);
      if (o < 16) qTb[((size_t)(b * 16 + o) << 12) + n] = bv;
      else        kbf[nqk + o - 16] = bv;
    }
#pragma unroll
    for (int r = 0; r < 16; ++r) {
      int o = 32 + 4 * h + (r & 3) + 8 * (r >> 2);
      vbf[VT(b, n, o - 32)] = f2bf_rne(acc[1][r] + bsh[o]);
    }
  } else {
#pragma unroll
    for (int r = 0; r < 16; ++r) {
      int o = otbase * 32 + 4 * h + (r & 3) + 8 * (r >> 2);
      vbf[VT(b, n, o - 32)] = f2bf_rne(acc[0][r] + bsh[o]);
    }
  }
}

// ---------------------------------------------------------------------------
// R15 flash attention + fused proj. Loop = R12 verbatim.
// ---------------------------------------------------------------------------
#define VS 24                     // shorts per V row (16 data + 8 pad)
#define OTS 136                   // O^T row stride in shorts (68 dwords)

__global__ __launch_bounds__(256)
void attn_kernel(const unsigned short* __restrict__ qTb,
                 const unsigned short* __restrict__ kbf,
                 const unsigned short* __restrict__ vbf,
                 const unsigned short* __restrict__ pwb,
                 const float* __restrict__ pb,
                 const float* __restrict__ x,
                 float* __restrict__ out) {
  __shared__ alignas(16) unsigned short smem[2][512 * VS];   // 49152 B
  __shared__ float l_lds[64];
  __shared__ float pbs[128];

  const int id = blockIdx.x;
  const int b = id & 7, i0 = (id >> 3) << 6;   // XCD-pinned batch, 64-i tile
  const int t = threadIdx.x;
  const int w = t >> 6, lane = t & 63, h = lane >> 5, l = lane & 31;
  const int jsub = w & 1, ihalf = w >> 1;

  const unsigned short* kg = kbf + ((size_t)b << 16);
  const unsigned short* vg = vbf + ((size_t)b << 19);

  if (t < 128) pbs[t] = pb[t];

  // Q B-frag from Q^T [B,16,N]: 8 coalesced b16 loads, once per kernel
  const int iglob = i0 + ihalf * 32 + l;
  unsigned qd[4];
#pragma unroll
  for (int e = 0; e < 4; ++e) {
    unsigned lo = qTb[((size_t)(b * 16 + 8 * h + 2 * e) << 12) + iglob];
    unsigned hi = qTb[((size_t)(b * 16 + 8 * h + 2 * e + 1) << 12) + iglob];
    qd[e] = lo | (hi << 16);
  }
  const v8s qf = mk8(qd[0], qd[1], qd[2], qd[3]);

  v16f zc;
#pragma unroll
  for (int r = 0; r < 16; ++r) zc[r] = 0.f;
  v16f acc[4];
#pragma unroll
  for (int ct = 0; ct < 4; ++ct)
#pragma unroll
    for (int r = 0; r < 16; ++r) acc[ct][r] = 0.f;
  float ls = 0.f;

  // staging: per thread 4 chunks: rows w*128 + (lane>>1) + {0,32,64,96}
  const int srow = w * 128 + (lane >> 1);
  const int sh16 = (lane & 1) * 8;

  // prologue: stage tile 0 into buf 0
#pragma unroll
  for (int u = 0; u < 4; ++u) {
    v8s a = *(const v8s*)(vg + (size_t)(srow + 32 * u) * 16 + sh16);
    *(v8s*)(&smem[0][(srow + 32 * u) * VS + sh16]) = a;
  }
  if (t < 64) l_lds[t] = 0.f;
  __syncthreads();

  for (int tile = 0; tile < 64; ++tile) {
    const int tn = (tile + 1) & 63;   // wrap: harmless reload on last iter
    unsigned short* const cur = smem[tile & 1];
    unsigned short* const nxt = smem[(tile + 1) & 1];

    // prefetch next V tile into regs (coalesced 2KB per wave-instr)
    v8s s[4];
#pragma unroll
    for (int u = 0; u < 4; ++u)
      s[u] = *(const v8s*)(vg + (size_t)tn * 8192 + (size_t)(srow + 32 * u) * 16 + sh16);

    // K A-frag direct from global (coalesced 1KB)
    v8s kf = *(const v8s*)(kg + (((size_t)(tile * 64 + jsub * 32 + l)) << 4) + 8 * h);

    // QK: S^T patch (rows j, cols i) -> P in regs
    v16f st = __builtin_amdgcn_mfma_f32_32x32x16_bf16(kf, qf, zc, 0, 0, 0);
    float pe[16];
#pragma unroll
    for (int r = 0; r < 16; ++r) { pe[r] = __builtin_amdgcn_exp2f(st[r]); ls += pe[r]; }
    unsigned G[8];
#pragma unroll
    for (int g = 0; g < 4; ++g) {
      G[2 * g]     = pack_trunc(pe[4 * g + 1], pe[4 * g]);
      G[2 * g + 1] = pack_trunc(pe[4 * g + 3], pe[4 * g + 2]);
    }
    // half-wave exchange (proven mapping): 4 shfl + selects
    unsigned S0 = h ? G[0] : G[2], S1 = h ? G[1] : G[3];
    unsigned S2 = h ? G[4] : G[6], S3 = h ? G[5] : G[7];
    unsigned R0 = (unsigned)__shfl_xor((int)S0, 32, 64);
    unsigned R1 = (unsigned)__shfl_xor((int)S1, 32, 64);
    unsigned R2 = (unsigned)__shfl_xor((int)S2, 32, 64);
    unsigned R3 = (unsigned)__shfl_xor((int)S3, 32, 64);
    v8s pf0 = h ? mk8(R0, R1, G[2], G[3]) : mk8(G[0], G[1], R0, R1);
    v8s pf1 = h ? mk8(R2, R3, G[6], G[7]) : mk8(G[4], G[5], R2, R3);

    // PV from cur (conflict-free b128 reads)
#pragma unroll
    for (int ct = 0; ct < 4; ++ct) {
      v8s vf0 = *(const v8s*)(&cur[((jsub * 2) * 128 + ct * 32 + l) * VS + 8 * h]);
      v8s vf1 = *(const v8s*)(&cur[((jsub * 2 + 1) * 128 + ct * 32 + l) * VS + 8 * h]);
      acc[ct] = __builtin_amdgcn_mfma_f32_32x32x16_bf16(vf0, pf0, acc[ct], 0, 0, 0);
      acc[ct] = __builtin_amdgcn_mfma_f32_32x32x16_bf16(vf1, pf1, acc[ct], 0, 0, 0);
    }

    // commit prefetched tile to nxt (no reader until after barrier)
#pragma unroll
    for (int u = 0; u < 4; ++u)
      *(v8s*)(&nxt[(srow + 32 * u) * VS + sh16]) = s[u];

    __syncthreads();
  }

  // ---- epilogue: jsub combine (R12), then fused proj ----
  atomicAdd(&l_lds[ihalf * 32 + l], ls);
  __syncthreads();   // all PV reads done; V buffers dead; l complete

  float* const ov = (float*)smem;   // f32 combine overlay
  if (jsub == 1) {
#pragma unroll
    for (int ct = 0; ct < 4; ++ct)
#pragma unroll
      for (int q = 0; q < 4; ++q) {
        float4 v4 = {acc[ct][4 * q], acc[ct][4 * q + 1],
                     acc[ct][4 * q + 2], acc[ct][4 * q + 3]};
        *(float4*)&ov[((ct * 2 + ihalf) * 32 + l) * 36 + 4 * h + 8 * q] = v4;
      }
  }
  __syncthreads();
  if (jsub == 0) {
#pragma unroll
    for (int ct = 0; ct < 4; ++ct)
#pragma unroll
      for (int q = 0; q < 4; ++q) {
        float4 v4 = *(float4*)&ov[((ct * 2 + ihalf) * 32 + l) * 36 + 4 * h + 8 * q];
        acc[ct][4 * q]     += v4.x;
        acc[ct][4 * q + 1] += v4.y;
        acc[ct][4 * q + 2] += v4.z;
        acc[ct][4 * q + 3] += v4.w;
      }
  }
  __syncthreads();   // ov reads complete; smem reusable

  // jsub=0 waves write normalized O^T bf16 [n_local][c], stride OTS
  unsigned short* const oT = (unsigned short*)smem;
  if (jsub == 0) {
    const float li = 1.f / l_lds[ihalf * 32 + l];
    const int nrow = ihalf * 32 + l;
#pragma unroll
    for (int ct = 0; ct < 4; ++ct)
#pragma unroll
      for (int r = 0; r < 16; r += 2) {
        int c = ct * 32 + 4 * h + (r & 3) + 8 * (r >> 2);   // even
        unsigned dw = (unsigned)f2bf_rne(acc[ct][r] * li) |
                      ((unsigned)f2bf_rne(acc[ct][r + 1] * li) << 16);
        *(unsigned*)(&oT[nrow * OTS + c]) = dw;
      }
  }
  __syncthreads();

  // fused proj: wave w -> e-tile w (32 e), both n-subs. out = pw@O + pb + x.
#pragma unroll
  for (int nsub = 0; nsub < 2; ++nsub) {
    v16f a2;
#pragma unroll
    for (int r = 0; r < 16; ++r) a2[r] = 0.f;
#pragma unroll
    for (int ks = 0; ks < 8; ++ks) {
      v8s bf = *(const v8s*)(&oT[(nsub * 32 + l) * OTS + ks * 16 + 8 * h]);
      v8s af = *(const v8s*)(pwb + (w * 32 + l) * 128 + ks * 16 + 8 * h);
      a2 = __builtin_amdgcn_mfma_f32_32x32x16_bf16(af, bf, a2, 0, 0, 0);
    }
    const int n = i0 + nsub * 32 + l;
#pragma unroll
    for (int r = 0; r < 16; ++r) {
      int e = w * 32 + 4 * h + (r & 3) + 8 * (r >> 2);
      size_t idx = ((size_t)(b * 128 + e) << 12) + n;
      out[idx] = a2[r] + pbs[e] + x[idx];
    }
  }
}

// ---------------------------------------------------------------------------
extern "C" void kernel_launch(void* const* d_in, const int* in_sizes, int n_in,
                              void* d_out, int out_size, void* d_ws, size_t ws_size,
                              hipStream_t stream) {
  const float* x   = (const float*)d_in[0];
  const float* gnw = (const float*)d_in[1];
  const float* gnb = (const float*)d_in[2];
  const float* qw  = (const float*)d_in[3];
  const float* qb  = (const float*)d_in[4];
  const float* kw  = (const float*)d_in[5];
  const float* kb  = (const float*)d_in[6];
  const float* vw  = (const float*)d_in[7];
  const float* vb  = (const float*)d_in[8];
  const float* pw  = (const float*)d_in[9];
  const float* pb  = (const float*)d_in[10];
  float* out = (float*)d_out;
  char* ws = (char*)d_ws;

  float* mu_rs = (float*)(ws + WSB_MURS);
  unsigned short* wcatb = (unsigned short*)(ws + WSB_WCATB);
  float* bcat = (float*)(ws + WSB_BCAT);
  unsigned short* pwb = (unsigned short*)(ws + WSB_PWB);
  unsigned short* qTb = (unsigned short*)(ws + WSB_QBF);
  unsigned short* kbf = (unsigned short*)(ws + WSB_KBF);
  unsigned short* vbf = (unsigned short*)(ws + WSB_VBF);

  hipLaunchKernelGGL(gnprep_kernel, dim3(256), dim3(512), 0, stream,
                     x, mu_rs, qw, qb, kw, kb, vw, vb, pw, wcatb, bcat, pwb);
  hipLaunchKernelGGL(qkv_kernel, dim3(512), dim3(512), 0, stream,
                     x, gnw, gnb, mu_rs, wcatb, bcat, qTb, kbf, vbf);
  hipLaunchKernelGGL(attn_kernel, dim3(512), dim3(256), 0, stream,
                     qTb, kbf, vbf, pwb, pb, x, out);
}

// Round 16
// 157.618 us; speedup vs baseline: 1.7072x; 1.0375x over previous
//
#include <hip/hip_runtime.h>
#include <math.h>

// B=8, C=128, N=4096, d=16, groups=32
// R16 = R15 (attn+proj fused, VERBATIM) + qkv rewritten as LDS-staged GEMM.
//   R15 ledger: attn 73.8 us, total 163.5 -> gnprep+qkv ~= 90 us vs ~10 us
//   memory floor. qkv's hoisted 64-deep scalar global_load chain (R7-style
//   latency serialization + 4x read redundancy) is the suspect.
//   New qkv: coalesced fp32 x loads (lane=consecutive n), GN inline, bf16
//   pack to LDS hs[n][c] stride 136 shorts (16B-aligned rows; b64 writes
//   2-way=free; b128 B-frag reads phase-disjoint=conflict-free), 1 barrier,
//   MFMA from LDS. Each x element read once per block.

typedef short v8s __attribute__((ext_vector_type(8)));   // 8 bf16 = 4 VGPRs
typedef float v16f __attribute__((ext_vector_type(16))); // 32x32 acc

__device__ __forceinline__ unsigned short f2bf_rne(float f) {
  unsigned u = __float_as_uint(f);
  u += 0x7fffu + ((u >> 16) & 1u);
  return (unsigned short)(u >> 16);
}

__device__ __forceinline__ v8s mk8(unsigned a, unsigned b, unsigned c, unsigned d) {
  union { unsigned u[4]; v8s s; } x;
  x.u[0] = a; x.u[1] = b; x.u[2] = c; x.u[3] = d;
  return x.s;
}

// pack two fp32 -> dword of 2 bf16 (truncation) in ONE v_perm_b32
__device__ __forceinline__ unsigned pack_trunc(float hi, float lo) {
  return __builtin_amdgcn_perm(__float_as_uint(hi), __float_as_uint(lo), 0x07060302u);
}

// tiled V element index: [b][j>>4][c][j&15]
#define VT(b, n, c) (((((size_t)(b) * 256 + ((n) >> 4)) << 7) + (c)) * 16 + ((n) & 15))

// ws byte offsets
#define WSB_MURS   0u
#define WSB_WCATB  4096u       // 160*128 bf16 = 40960
#define WSB_BCAT   49152u      // 160 f32
#define WSB_PWB    65536u      // 128*128 bf16 = 32768
#define WSB_QBF    131072u     // Q^T [B,16,N] bf16 = 1 MB
#define WSB_KBF    1310720u    // K [B,N,16] bf16 = 1 MB
#define WSB_VBF    2621440u    // 8 MB (tiled)

// ---------------------------------------------------------------------------
// gn_stats + prep fused. Grid 256 x 512 thr.
// ---------------------------------------------------------------------------
__global__ __launch_bounds__(512)
void gnprep_kernel(const float* __restrict__ x, float* __restrict__ mu_rs,
                   const float* __restrict__ qw, const float* __restrict__ qb,
                   const float* __restrict__ kw, const float* __restrict__ kb,
                   const float* __restrict__ vw, const float* __restrict__ vb,
                   const float* __restrict__ pw,
                   unsigned short* __restrict__ wcatb, float* __restrict__ bcat,
                   unsigned short* __restrict__ pwb) {
  const int id = blockIdx.x;
  {
    const float qs = 0.36067376022224085f;  // 0.25 * log2(e)
    int idx = id * 512 + threadIdx.x;
    if (idx < 160 * 128) {
      int o = idx >> 7, c = idx & 127;
      float val;
      if (o < 16)       val = qw[o * 128 + c] * qs;
      else if (o < 32)  val = kw[(o - 16) * 128 + c];
      else              val = vw[(o - 32) * 128 + c];
      wcatb[idx] = f2bf_rne(val);
    } else if (idx < 160 * 128 + 160) {
      int o = idx - 160 * 128;
      bcat[o] = (o < 16) ? qb[o] * qs : (o < 32) ? kb[o - 16] : vb[o - 32];
    } else if (idx < 160 * 128 + 160 + 128 * 128) {
      int j = idx - (160 * 128 + 160);
      pwb[j] = f2bf_rne(pw[j]);
    }
  }
  const int bg = (id & 7) * 32 + (id >> 3);   // XCD swizzle: batch = id & 7
  const float4* xp = (const float4*)(x + (size_t)bg * 16384);
  float s = 0.f, ss = 0.f;
#pragma unroll
  for (int u = 0; u < 8; ++u) {
    int i = threadIdx.x + u * 512;
    float4 v = xp[i];
    s  += v.x + v.y + v.z + v.w;
    ss += v.x * v.x + v.y * v.y + v.z * v.z + v.w * v.w;
  }
  for (int off = 32; off > 0; off >>= 1) {
    s  += __shfl_down(s, off, 64);
    ss += __shfl_down(ss, off, 64);
  }
  __shared__ float red[16];
  int lane = threadIdx.x & 63, wid = threadIdx.x >> 6;
  if (lane == 0) { red[wid * 2] = s; red[wid * 2 + 1] = ss; }
  __syncthreads();
  if (threadIdx.x == 0) {
    float S = 0.f, SS = 0.f;
    for (int w = 0; w < 8; ++w) { S += red[w * 2]; SS += red[w * 2 + 1]; }
    float mu  = S * (1.0f / 16384.0f);
    float var = SS * (1.0f / 16384.0f) - mu * mu;
    float rs  = rsqrtf(var + 1e-5f);
    mu_rs[bg * 2]     = mu;
    mu_rs[bg * 2 + 1] = rs;
  }
}

// ---------------------------------------------------------------------------
// R16 QKV: LDS-staged GEMM. Block 512 thr (8 waves), n-tile 64, grid 512,
// XCD-pinned. Stage x (GN'd, bf16) into hs[n][c] stride 136, then MFMA.
// ---------------------------------------------------------------------------
#define HS 136   // shorts per hs row (128 data + 8 pad); 16B-aligned rows

__global__ __launch_bounds__(512)
void qkv_kernel(const float* __restrict__ x, const float* __restrict__ gnw,
                const float* __restrict__ gnb, const float* __restrict__ mu_rs,
                const unsigned short* __restrict__ wcatb, const float* __restrict__ bcat,
                unsigned short* __restrict__ qTb, unsigned short* __restrict__ kbf,
                unsigned short* __restrict__ vbf) {
  __shared__ alignas(16) unsigned short hs[64 * HS];   // 17408 B
  __shared__ float scsh[128], shsh[128], bsh[160];
  const int id = blockIdx.x;
  const int b = id & 7, nb = (id >> 3) << 6;   // XCD-pinned batch
  const int t = threadIdx.x;
  const int w = t >> 6, lane = t & 63, h = lane >> 5, l = lane & 31;
  const int nsub = w & 1, og = w >> 1;

  if (t < 128) {
    float mu = mu_rs[(b * 32 + (t >> 2)) * 2];
    float rs = mu_rs[(b * 32 + (t >> 2)) * 2 + 1];
    float gw = gnw[t], gb = gnb[t];
    scsh[t] = rs * gw; shsh[t] = gb - mu * rs * gw;
  }
  if (t < 160) bsh[t] = bcat[t];
  __syncthreads();

  // ---- stage: thread = (sn = t&63, c-quad base c00 = (t>>6)*4), 4 iters ----
  const int sn = t & 63;
  const int c00 = (t >> 6) * 4;
  const float* xb = x + ((size_t)b * 128 << 12) + nb + sn;
#pragma unroll
  for (int it = 0; it < 4; ++it) {
    const int c0 = c00 + it * 32;    // wave-uniform
    float f0 = xb[(size_t)(c0)     << 12] * scsh[c0]     + shsh[c0];
    float f1 = xb[(size_t)(c0 + 1) << 12] * scsh[c0 + 1] + shsh[c0 + 1];
    float f2 = xb[(size_t)(c0 + 2) << 12] * scsh[c0 + 2] + shsh[c0 + 2];
    float f3 = xb[(size_t)(c0 + 3) << 12] * scsh[c0 + 3] + shsh[c0 + 3];
    uint2 u;
    u.x = (unsigned)f2bf_rne(f0) | ((unsigned)f2bf_rne(f1) << 16);
    u.y = (unsigned)f2bf_rne(f2) | ((unsigned)f2bf_rne(f3) << 16);
    *(uint2*)(&hs[sn * HS + c0]) = u;
  }
  __syncthreads();

  // ---- MFMA: wave (nsub, og); og0 -> ot{0,1}, og1..3 -> ot{2..4} ----
  const int n = nb + nsub * 32 + l;
  const int otbase = (og == 0) ? 0 : og + 1;
  v16f acc[2];
#pragma unroll
  for (int a2 = 0; a2 < 2; ++a2)
#pragma unroll
    for (int r = 0; r < 16; ++r) acc[a2][r] = 0.f;

#pragma unroll
  for (int ks = 0; ks < 8; ++ks) {
    v8s bf = *(const v8s*)(&hs[(nsub * 32 + l) * HS + ks * 16 + 8 * h]);
    {
      v8s af = *(const v8s*)(wcatb + (otbase * 32 + l) * 128 + ks * 16 + 8 * h);
      acc[0] = __builtin_amdgcn_mfma_f32_32x32x16_bf16(af, bf, acc[0], 0, 0, 0);
    }
    if (og == 0) {
      v8s af = *(const v8s*)(wcatb + (32 + l) * 128 + ks * 16 + 8 * h);
      acc[1] = __builtin_amdgcn_mfma_f32_32x32x16_bf16(af, bf, acc[1], 0, 0, 0);
    }
  }

  // ---- epilogue (unchanged) ----
  if (og == 0) {
    const size_t nqk = ((size_t)b * 4096 + n) << 4;
#pragma unroll
    for (int r = 0; r < 16; ++r) {
      int o = 4 * h + (r & 3) + 8 * (r >> 2);
      unsigned short bv = f2bf_rne(acc[0][r] + bsh[o]);
      if (o < 16) qTb[((size_t)(b * 16 + o) << 12) + n] = bv;
      else        kbf[nqk + o - 16] = bv;
    }
#pragma unroll
    for (int r = 0; r < 16; ++r) {
      int o = 32 + 4 * h + (r & 3) + 8 * (r >> 2);
      vbf[VT(b, n, o - 32)] = f2bf_rne(acc[1][r] + bsh[o]);
    }
  } else {
#pragma unroll
    for (int r = 0; r < 16; ++r) {
      int o = otbase * 32 + 4 * h + (r & 3) + 8 * (r >> 2);
      vbf[VT(b, n, o - 32)] = f2bf_rne(acc[0][r] + bsh[o]);
    }
  }
}

// ---------------------------------------------------------------------------
// R15 flash attention + fused proj (VERBATIM from R15).
// ---------------------------------------------------------------------------
#define VS 24                     // shorts per V row (16 data + 8 pad)
#define OTS 136                   // O^T row stride in shorts (68 dwords)

__global__ __launch_bounds__(256)
void attn_kernel(const unsigned short* __restrict__ qTb,
                 const unsigned short* __restrict__ kbf,
                 const unsigned short* __restrict__ vbf,
                 const unsigned short* __restrict__ pwb,
                 const float* __restrict__ pb,
                 const float* __restrict__ x,
                 float* __restrict__ out) {
  __shared__ alignas(16) unsigned short smem[2][512 * VS];   // 49152 B
  __shared__ float l_lds[64];
  __shared__ float pbs[128];

  const int id = blockIdx.x;
  const int b = id & 7, i0 = (id >> 3) << 6;   // XCD-pinned batch, 64-i tile
  const int t = threadIdx.x;
  const int w = t >> 6, lane = t & 63, h = lane >> 5, l = lane & 31;
  const int jsub = w & 1, ihalf = w >> 1;

  const unsigned short* kg = kbf + ((size_t)b << 16);
  const unsigned short* vg = vbf + ((size_t)b << 19);

  if (t < 128) pbs[t] = pb[t];

  // Q B-frag from Q^T [B,16,N]: 8 coalesced b16 loads, once per kernel
  const int iglob = i0 + ihalf * 32 + l;
  unsigned qd[4];
#pragma unroll
  for (int e = 0; e < 4; ++e) {
    unsigned lo = qTb[((size_t)(b * 16 + 8 * h + 2 * e) << 12) + iglob];
    unsigned hi = qTb[((size_t)(b * 16 + 8 * h + 2 * e + 1) << 12) + iglob];
    qd[e] = lo | (hi << 16);
  }
  const v8s qf = mk8(qd[0], qd[1], qd[2], qd[3]);

  v16f zc;
#pragma unroll
  for (int r = 0; r < 16; ++r) zc[r] = 0.f;
  v16f acc[4];
#pragma unroll
  for (int ct = 0; ct < 4; ++ct)
#pragma unroll
    for (int r = 0; r < 16; ++r) acc[ct][r] = 0.f;
  float ls = 0.f;

  // staging: per thread 4 chunks: rows w*128 + (lane>>1) + {0,32,64,96}
  const int srow = w * 128 + (lane >> 1);
  const int sh16 = (lane & 1) * 8;

  // prologue: stage tile 0 into buf 0
#pragma unroll
  for (int u = 0; u < 4; ++u) {
    v8s a = *(const v8s*)(vg + (size_t)(srow + 32 * u) * 16 + sh16);
    *(v8s*)(&smem[0][(srow + 32 * u) * VS + sh16]) = a;
  }
  if (t < 64) l_lds[t] = 0.f;
  __syncthreads();

  for (int tile = 0; tile < 64; ++tile) {
    const int tn = (tile + 1) & 63;   // wrap: harmless reload on last iter
    unsigned short* const cur = smem[tile & 1];
    unsigned short* const nxt = smem[(tile + 1) & 1];

    // prefetch next V tile into regs (coalesced 2KB per wave-instr)
    v8s s[4];
#pragma unroll
    for (int u = 0; u < 4; ++u)
      s[u] = *(const v8s*)(vg + (size_t)tn * 8192 + (size_t)(srow + 32 * u) * 16 + sh16);

    // K A-frag direct from global (coalesced 1KB)
    v8s kf = *(const v8s*)(kg + (((size_t)(tile * 64 + jsub * 32 + l)) << 4) + 8 * h);

    // QK: S^T patch (rows j, cols i) -> P in regs
    v16f st = __builtin_amdgcn_mfma_f32_32x32x16_bf16(kf, qf, zc, 0, 0, 0);
    float pe[16];
#pragma unroll
    for (int r = 0; r < 16; ++r) { pe[r] = __builtin_amdgcn_exp2f(st[r]); ls += pe[r]; }
    unsigned G[8];
#pragma unroll
    for (int g = 0; g < 4; ++g) {
      G[2 * g]     = pack_trunc(pe[4 * g + 1], pe[4 * g]);
      G[2 * g + 1] = pack_trunc(pe[4 * g + 3], pe[4 * g + 2]);
    }
    // half-wave exchange (proven mapping): 4 shfl + selects
    unsigned S0 = h ? G[0] : G[2], S1 = h ? G[1] : G[3];
    unsigned S2 = h ? G[4] : G[6], S3 = h ? G[5] : G[7];
    unsigned R0 = (unsigned)__shfl_xor((int)S0, 32, 64);
    unsigned R1 = (unsigned)__shfl_xor((int)S1, 32, 64);
    unsigned R2 = (unsigned)__shfl_xor((int)S2, 32, 64);
    unsigned R3 = (unsigned)__shfl_xor((int)S3, 32, 64);
    v8s pf0 = h ? mk8(R0, R1, G[2], G[3]) : mk8(G[0], G[1], R0, R1);
    v8s pf1 = h ? mk8(R2, R3, G[6], G[7]) : mk8(G[4], G[5], R2, R3);

    // PV from cur (conflict-free b128 reads)
#pragma unroll
    for (int ct = 0; ct < 4; ++ct) {
      v8s vf0 = *(const v8s*)(&cur[((jsub * 2) * 128 + ct * 32 + l) * VS + 8 * h]);
      v8s vf1 = *(const v8s*)(&cur[((jsub * 2 + 1) * 128 + ct * 32 + l) * VS + 8 * h]);
      acc[ct] = __builtin_amdgcn_mfma_f32_32x32x16_bf16(vf0, pf0, acc[ct], 0, 0, 0);
      acc[ct] = __builtin_amdgcn_mfma_f32_32x32x16_bf16(vf1, pf1, acc[ct], 0, 0, 0);
    }

    // commit prefetched tile to nxt (no reader until after barrier)
#pragma unroll
    for (int u = 0; u < 4; ++u)
      *(v8s*)(&nxt[(srow + 32 * u) * VS + sh16]) = s[u];

    __syncthreads();
  }

  // ---- epilogue: jsub combine, then fused proj ----
  atomicAdd(&l_lds[ihalf * 32 + l], ls);
  __syncthreads();   // all PV reads done; V buffers dead; l complete

  float* const ov = (float*)smem;   // f32 combine overlay
  if (jsub == 1) {
#pragma unroll
    for (int ct = 0; ct < 4; ++ct)
#pragma unroll
      for (int q = 0; q < 4; ++q) {
        float4 v4 = {acc[ct][4 * q], acc[ct][4 * q + 1],
                     acc[ct][4 * q + 2], acc[ct][4 * q + 3]};
        *(float4*)&ov[((ct * 2 + ihalf) * 32 + l) * 36 + 4 * h + 8 * q] = v4;
      }
  }
  __syncthreads();
  if (jsub == 0) {
#pragma unroll
    for (int ct = 0; ct < 4; ++ct)
#pragma unroll
      for (int q = 0; q < 4; ++q) {
        float4 v4 = *(float4*)&ov[((ct * 2 + ihalf) * 32 + l) * 36 + 4 * h + 8 * q];
        acc[ct][4 * q]     += v4.x;
        acc[ct][4 * q + 1] += v4.y;
        acc[ct][4 * q + 2] += v4.z;
        acc[ct][4 * q + 3] += v4.w;
      }
  }
  __syncthreads();   // ov reads complete; smem reusable

  // jsub=0 waves write normalized O^T bf16 [n_local][c], stride OTS
  unsigned short* const oT = (unsigned short*)smem;
  if (jsub == 0) {
    const float li = 1.f / l_lds[ihalf * 32 + l];
    const int nrow = ihalf * 32 + l;
#pragma unroll
    for (int ct = 0; ct < 4; ++ct)
#pragma unroll
      for (int r = 0; r < 16; r += 2) {
        int c = ct * 32 + 4 * h + (r & 3) + 8 * (r >> 2);   // even
        unsigned dw = (unsigned)f2bf_rne(acc[ct][r] * li) |
                      ((unsigned)f2bf_rne(acc[ct][r + 1] * li) << 16);
        *(unsigned*)(&oT[nrow * OTS + c]) = dw;
      }
  }
  __syncthreads();

  // fused proj: wave w -> e-tile w (32 e), both n-subs. out = pw@O + pb + x.
#pragma unroll
  for (int nsub = 0; nsub < 2; ++nsub) {
    v16f a2;
#pragma unroll
    for (int r = 0; r < 16; ++r) a2[r] = 0.f;
#pragma unroll
    for (int ks = 0; ks < 8; ++ks) {
      v8s bf = *(const v8s*)(&oT[(nsub * 32 + l) * OTS + ks * 16 + 8 * h]);
      v8s af = *(const v8s*)(pwb + (w * 32 + l) * 128 + ks * 16 + 8 * h);
      a2 = __builtin_amdgcn_mfma_f32_32x32x16_bf16(af, bf, a2, 0, 0, 0);
    }
    const int n = i0 + nsub * 32 + l;
#pragma unroll
    for (int r = 0; r < 16; ++r) {
      int e = w * 32 + 4 * h + (r & 3) + 8 * (r >> 2);
      size_t idx = ((size_t)(b * 128 + e) << 12) + n;
      out[idx] = a2[r] + pbs[e] + x[idx];
    }
  }
}

// ---------------------------------------------------------------------------
extern "C" void kernel_launch(void* const* d_in, const int* in_sizes, int n_in,
                              void* d_out, int out_size, void* d_ws, size_t ws_size,
                              hipStream_t stream) {
  const float* x   = (const float*)d_in[0];
  const float* gnw = (const float*)d_in[1];
  const float* gnb = (const float*)d_in[2];
  const float* qw  = (const float*)d_in[3];
  const float* qb  = (const float*)d_in[4];
  const float* kw  = (const float*)d_in[5];
  const float* kb  = (const float*)d_in[6];
  const float* vw  = (const float*)d_in[7];
  const float* vb  = (const float*)d_in[8];
  const float* pw  = (const float*)d_in[9];
  const float* pb  = (const float*)d_in[10];
  float* out = (float*)d_out;
  char* ws = (char*)d_ws;

  float* mu_rs = (float*)(ws + WSB_MURS);
  unsigned short* wcatb = (unsigned short*)(ws + WSB_WCATB);
  float* bcat = (float*)(ws + WSB_BCAT);
  unsigned short* pwb = (unsigned short*)(ws + WSB_PWB);
  unsigned short* qTb = (unsigned short*)(ws + WSB_QBF);
  unsigned short* kbf = (unsigned short*)(ws + WSB_KBF);
  unsigned short* vbf = (unsigned short*)(ws + WSB_VBF);

  hipLaunchKernelGGL(gnprep_kernel, dim3(256), dim3(512), 0, stream,
                     x, mu_rs, qw, qb, kw, kb, vw, vb, pw, wcatb, bcat, pwb);
  hipLaunchKernelGGL(qkv_kernel, dim3(512), dim3(512), 0, stream,
                     x, gnw, gnb, mu_rs, wcatb, bcat, qTb, kbf, vbf);
  hipLaunchKernelGGL(attn_kernel, dim3(512), dim3(256), 0, stream,
                     qTb, kbf, vbf, pwb, pb, x, out);
}